// Round 3
// baseline (615.154 us; speedup 1.0000x reference)
//
#include <hip/hip_runtime.h>
#include <cstdint>
#include <cstddef>

// Top-1 MoE gate. s=8192, e=64, d=2048, cap=128.
// d_out (float32): [l_aux(1), combine(8192*64*128), mask(8192*64*128)]
// 3-kernel pipeline, fence-free (kernel boundaries provide all ordering):
//   k1 gemm_softmax_zero_a: 256 fused blocks (32-token full-K GEMM with
//        per-slice sub-accumulators == split-K numerics, then in-block
//        softmax/argmax -> idx/gate, per-expert prob partial -> gpart)
//        + 768 blocks zero region A (~236 MB). No P buffer at all.
//   k2 scan_zero_b: block 0 = ballot-rank scan -> loc[] + gsum reduce + l_aux;
//        blocks 1-511 zero region B (~300 MB), concurrent with scan.
//   k3 scatter: 32 blocks, 2 stores per surviving token into zeroed output.
// HBM balance: k1 ~ 64(x)+236(zeros) = 300 MB, k2 ~ 300(zeros) = 300 MB.

#define S_TOK 8192
#define NEXP 64
#define DIM 2048
#define CAP 128
#define COMB_ELEMS ((size_t)S_TOK * NEXP * CAP)   // 67108864
#define OUT_ELEMS (1 + 2 * COMB_ELEMS)            // 134217729
#define NQUAD ((size_t)(OUT_ELEMS / 4))           // 33554432 quads cover all but last elem

// Split so k1 total HBM bytes ~= k2 total HBM bytes (see header comment).
#define QA ((size_t)14777216)   // region A: [0, QA)     ~236.4 MB (k1)
                                // region B: [QA, NQUAD) ~300.4 MB (k2)

#define TOK_TILE 32
#define NSLICE 4
#define KSLICE (DIM / NSLICE)   // 512
#define KC 32
#define NCHUNK (DIM / KC)       // 64

__device__ __forceinline__ void zero_quads(float* __restrict__ out,
                                           size_t q_begin, size_t q_end,
                                           int nblocks, int bid) {
    const float4 z = { 0.0f, 0.0f, 0.0f, 0.0f };
    size_t stride = (size_t)nblocks * blockDim.x;
    for (size_t q = q_begin + (size_t)bid * blockDim.x + threadIdx.x;
         q < q_end; q += stride)
        *(float4*)(out + 4 * q) = z;
}

// ---------------------------------------------------------------------------
// Kernel 1: fused full-K GEMM + softmax/argmax (blocks 0-255, 32 tokens each)
//           + zero region A (blocks 256-1023).
// Numerics: per-thread accumulator per 512-K slice, slices folded in ascending
// order -> bit-identical logits to the proven split-K(4) kernel.
// ---------------------------------------------------------------------------
__global__ __launch_bounds__(256, 4) void gemm_softmax_zero_a(
    const float* __restrict__ x, const float* __restrict__ wg,
    int* __restrict__ idx_out, float* __restrict__ gate_out,
    float* __restrict__ gpart, float* __restrict__ out)
{
    const int tid = threadIdx.x;

    if (blockIdx.x >= 256) {
        const int zb = blockIdx.x - 256;
        zero_quads(out, 0, QA, 768, zb);
        if (zb == 0 && tid == 0) out[OUT_ELEMS - 1] = 0.0f;  // odd tail element
        return;
    }

    __shared__ float xs[KC][34];    // [k][token], +2 pad keeps float2 rows aligned
    __shared__ float wsh[KC][68];   // [k][expert], +4 pad
    __shared__ float sme[NEXP];

    const int tok0 = blockIdx.x * TOK_TILE;
    const int tt = tid >> 4;        // 0..15: token pair {2tt, 2tt+1}
    const int te = tid & 15;        // 0..15: expert quad {4te..4te+3}

    // staging roles
    const int xt = tid >> 3;        // 0..31 token row
    const int xk = tid & 7;         // float4 index in 32-k chunk
    const int es = tid >> 3;        // 0..31 expert row (wv0); +32 for wv1
    // (es == xt; separate names for clarity)

    float l[8];                     // [token in pair][4 experts], running slice sum
#pragma unroll
    for (int o = 0; o < 8; ++o) l[o] = 0.0f;

    // preload chunk 0
    float4 xv  = *(const float4*)(x  + (size_t)(tok0 + xt) * DIM + 4 * xk);
    float4 wv0 = *(const float4*)(wg + (size_t)es * DIM + 4 * xk);
    float4 wv1 = *(const float4*)(wg + (size_t)(es + 32) * DIM + 4 * xk);

#pragma unroll
    for (int s = 0; s < NSLICE; ++s) {
        float acc[8];
#pragma unroll
        for (int o = 0; o < 8; ++o) acc[o] = 0.0f;

        for (int kci = 0; kci < KSLICE / KC; ++kci) {   // 16 iterations
            const int c = s * (KSLICE / KC) + kci;
            __syncthreads();
            xs[4 * xk + 0][xt] = xv.x; xs[4 * xk + 1][xt] = xv.y;
            xs[4 * xk + 2][xt] = xv.z; xs[4 * xk + 3][xt] = xv.w;
            wsh[4 * xk + 0][es] = wv0.x; wsh[4 * xk + 1][es] = wv0.y;
            wsh[4 * xk + 2][es] = wv0.z; wsh[4 * xk + 3][es] = wv0.w;
            wsh[4 * xk + 0][es + 32] = wv1.x; wsh[4 * xk + 1][es + 32] = wv1.y;
            wsh[4 * xk + 2][es + 32] = wv1.z; wsh[4 * xk + 3][es + 32] = wv1.w;
            __syncthreads();
            if (c + 1 < NCHUNK) {
                const int kb = KC * (c + 1);
                xv  = *(const float4*)(x  + (size_t)(tok0 + xt) * DIM + kb + 4 * xk);
                wv0 = *(const float4*)(wg + (size_t)es * DIM + kb + 4 * xk);
                wv1 = *(const float4*)(wg + (size_t)(es + 32) * DIM + kb + 4 * xk);
            }
#pragma unroll 8
            for (int k = 0; k < KC; ++k) {
                float2 a = *(const float2*)&xs[k][2 * tt];
                float4 b = *(const float4*)&wsh[k][4 * te];
                const float* bp = &b.x;
#pragma unroll
                for (int j = 0; j < 4; ++j) {
                    acc[j]     += a.x * bp[j];
                    acc[4 + j] += a.y * bp[j];
                }
            }
        }
#pragma unroll
        for (int o = 0; o < 8; ++o) l[o] += acc[o];   // ascending-slice fold
    }

    // ----- in-block softmax / argmax / per-expert prob partials -----
    if (tid < NEXP) sme[tid] = 0.0f;
    __syncthreads();

#pragma unroll
    for (int g = 0; g < 2; ++g) {
        const float l0 = l[4 * g + 0], l1 = l[4 * g + 1];
        const float l2 = l[4 * g + 2], l3 = l[4 * g + 3];
        // local argmax, lowest-index tie-break
        float v = l0; int ix = 4 * te;
        if (l1 > v) { v = l1; ix = 4 * te + 1; }
        if (l2 > v) { v = l2; ix = 4 * te + 2; }
        if (l3 > v) { v = l3; ix = 4 * te + 3; }
#pragma unroll
        for (int off = 8; off; off >>= 1) {
            float ov = __shfl_xor(v, off, 16);
            int   oi = __shfl_xor(ix, off, 16);
            if (ov > v || (ov == v && oi < ix)) { v = ov; ix = oi; }
        }
        float z0 = __expf(l0 - v), z1 = __expf(l1 - v);
        float z2 = __expf(l2 - v), z3 = __expf(l3 - v);
        float zs = ((z0 + z1) + z2) + z3;
#pragma unroll
        for (int off = 8; off; off >>= 1) zs += __shfl_xor(zs, off, 16);
        const float inv = 1.0f / zs;
        const int tok = tok0 + 2 * tt + g;
        if (te == 0) {
            idx_out[tok]  = ix;
            gate_out[tok] = inv;     // winning gate = exp(0)/zs
        }
        atomicAdd(&sme[4 * te + 0], z0 * inv);
        atomicAdd(&sme[4 * te + 1], z1 * inv);
        atomicAdd(&sme[4 * te + 2], z2 * inv);
        atomicAdd(&sme[4 * te + 3], z3 * inv);
    }
    __syncthreads();
    if (tid < NEXP) gpart[(size_t)blockIdx.x * NEXP + tid] = sme[tid];
}

// ---------------------------------------------------------------------------
// Kernel 2: block 0 = ballot-rank scan -> loc[] + gsum reduce + l_aux;
//           blocks 1-511 zero region B. 1024 threads.
// ---------------------------------------------------------------------------
__global__ __launch_bounds__(1024) void scan_zero_b(
    const int* __restrict__ idx, const float* __restrict__ gpart,
    int* __restrict__ loc_out, float* __restrict__ out)
{
    const int tid = threadIdx.x;

    if (blockIdx.x > 0) {
        zero_quads(out, QA, NQUAD, 511, (int)blockIdx.x - 1);
        return;
    }

    __shared__ int   wavecnt[16][NEXP];
    __shared__ int   basecnt[NEXP];
    __shared__ float fsum[16][NEXP];
    const int lane = tid & 63;
    const int wv   = tid >> 6;

    if (tid < NEXP) basecnt[tid] = 0;
    __syncthreads();

    for (int it = 0; it < S_TOK / 1024; ++it) {
        int tok = it * 1024 + tid;
        int e = idx[tok];
        unsigned long long m = ~0ull, lm = ~0ull;
#pragma unroll
        for (int b = 0; b < 6; ++b) {
            unsigned long long bal = __ballot((e >> b) & 1);
            m  &= ((e >> b) & 1)    ? bal : ~bal;
            lm &= ((lane >> b) & 1) ? bal : ~bal;
        }
        int rank = __popcll(m & ((1ull << lane) - 1ull));
        wavecnt[wv][lane] = __popcll(lm);
        __syncthreads();
        int off = 0;
        for (int w = 0; w < wv; ++w) off += wavecnt[w][e];
        loc_out[tok] = basecnt[e] + off + rank;   // >= CAP means dropped
        __syncthreads();
        if (tid < NEXP) {
            int tot = 0;
#pragma unroll
            for (int w = 0; w < 16; ++w) tot += wavecnt[w][tid];
            basecnt[tid] += tot;
        }
        __syncthreads();
    }

    // gsum = column sums of gpart[256][64]; then l_aux
    {
        float g = 0.0f;
#pragma unroll
        for (int r = 0; r < 16; ++r)
            g += gpart[(size_t)(wv * 16 + r) * NEXP + lane];
        fsum[wv][lane] = g;
    }
    __syncthreads();
    if (tid < NEXP) {
        float g = 0.0f;
#pragma unroll
        for (int w = 0; w < 16; ++w) g += fsum[w][tid];
        float p = g * (float)basecnt[tid];
#pragma unroll
        for (int off = 32; off; off >>= 1) p += __shfl_xor(p, off, 64);
        if (tid == 0) out[0] = p * 9.5367431640625e-07f;  // 64/8192^2
    }
}

// ---------------------------------------------------------------------------
// Kernel 3: sparse scatter into fully-zeroed output. One token per thread.
// ---------------------------------------------------------------------------
__global__ __launch_bounds__(256) void scatter_kernel(
    const int* __restrict__ idx, const float* __restrict__ gate,
    const int* __restrict__ loc, float* __restrict__ out)
{
    int t = blockIdx.x * 256 + threadIdx.x;
    int l = loc[t];
    if (l < CAP) {
        size_t base = 1 + (size_t)t * (NEXP * CAP) + (size_t)idx[t] * CAP + l;
        out[base] = gate[t];              // combine_weights
        out[base + COMB_ELEMS] = 1.0f;    // dispatch_mask
    }
}

extern "C" void kernel_launch(void* const* d_in, const int* in_sizes, int n_in,
                              void* d_out, int out_size, void* d_ws, size_t ws_size,
                              hipStream_t stream) {
    const float* x  = (const float*)d_in[0];   // [8192, 2048] fp32
    const float* wg = (const float*)d_in[1];   // [64, 2048] fp32
    float* out = (float*)d_out;

    // ws layout
    int*   idx   = (int*)d_ws;                            // 32 KB
    float* gate  = (float*)((char*)d_ws + 32768);         // 32 KB
    int*   loc   = (int*)((char*)d_ws + 65536);           // 32 KB
    float* gpart = (float*)((char*)d_ws + 131072);        // 64 KB [256][64]

    gemm_softmax_zero_a<<<1024, 256, 0, stream>>>(x, wg, idx, gate, gpart, out);
    scan_zero_b<<<512, 1024, 0, stream>>>(idx, gpart, loc, out);
    scatter_kernel<<<S_TOK / 256, 256, 0, stream>>>(idx, gate, loc, out);
}

// Round 6
// 586.962 us; speedup vs baseline: 1.0480x; 1.0480x over previous
//
#include <hip/hip_runtime.h>
#include <cstdint>
#include <cstddef>

// Top-1 MoE gate. s=8192, e=64, d=2048, cap=128.
// d_out (float32): [l_aux(1), combine(8192*64*128), mask(8192*64*128)]
// Proven 4-kernel pipeline (round-0 structure, 591 us) + non-temporal zero
// stores (537 MB of streaming zeros no longer write-allocate in the
// 4 MiB/XCD L2s). Native clang vector type for the nt builtin (HIP float4
// is a class type the builtin rejects).
//   k1 gemm_zero_a : 256 split-K GEMM blocks + 768 blocks zero region A
//   k2 reduce_zero_b: 256 reduce blocks (softmax/argmax/gsum) + 768 zero B
//   k3 scan_zero_c : block 0 ballot-rank scan (loc + l_aux) + 256 zero C
//   k4 scatter     : 2 stores per surviving token into pre-zeroed output

#define S_TOK 8192
#define NEXP 64
#define DIM 2048
#define CAP 128
#define COMB_ELEMS ((size_t)S_TOK * NEXP * CAP)   // 67108864
#define OUT_ELEMS (1 + 2 * COMB_ELEMS)            // 134217729
#define NQUAD ((size_t)(OUT_ELEMS / 4))           // 33554432 quads cover all but last elem

#define QA ((size_t)14000000)   // region A: [0, QA)          ~224 MB (k1)
#define QB ((size_t)24000000)   // region B: [QA, QB)         ~160 MB (k2)
                                // region C: [QB, NQUAD)      ~153 MB (k3)

#define TOK_TILE 128
#define NSLICE 4
#define KSLICE (DIM / NSLICE)   // 512
#define KC 32

typedef float vf4 __attribute__((ext_vector_type(4)));   // clang vector: nt-builtin-legal

__device__ __forceinline__ void zero_quads(float* __restrict__ out,
                                           size_t q_begin, size_t q_end,
                                           int nblocks, int bid) {
    const vf4 z = { 0.0f, 0.0f, 0.0f, 0.0f };
    size_t stride = (size_t)nblocks * blockDim.x;
    for (size_t q = q_begin + (size_t)bid * blockDim.x + threadIdx.x;
         q < q_end; q += stride)
        __builtin_nontemporal_store(z, (vf4*)(out + 4 * q));
}

// ---------------------------------------------------------------------------
// Kernel 1: split-K logits GEMM (blocks 0-255) + zero region A (blocks 256-1023)
// ---------------------------------------------------------------------------
__global__ __launch_bounds__(256, 4) void gemm_zero_a(
    const float* __restrict__ x, const float* __restrict__ wg,
    float* __restrict__ P, float* __restrict__ gsum,
    float* __restrict__ out)
{
    const int tid = threadIdx.x;

    if (blockIdx.x >= 256) {
        const int zb = blockIdx.x - 256;
        zero_quads(out, 0, QA, 768, zb);
        if (zb == 0 && tid == 0) out[OUT_ELEMS - 1] = 0.0f;  // odd tail element
        return;
    }

    __shared__ float xs[KC][132];
    __shared__ float wsh[KC][68];

    const int tile  = blockIdx.x >> 2;
    const int slice = blockIdx.x & 3;
    const int tok0 = tile * TOK_TILE;
    const int k0   = slice * KSLICE;

    if (blockIdx.x == 0 && tid < NEXP) gsum[tid] = 0.0f;

    const int tt = tid >> 4;
    const int te = tid & 15;

    float acc[8][4];
#pragma unroll
    for (int i = 0; i < 8; ++i)
#pragma unroll
        for (int j = 0; j < 4; ++j) acc[i][j] = 0.0f;

    const int we  = tid & 63;
    const int wkq = tid >> 6;

    float4 xv[4], wv[2];
#pragma unroll
    for (int r = 0; r < 4; ++r) {
        int idx = tid + 256 * r;
        int t = idx >> 3, kq = idx & 7;
        xv[r] = *(const float4*)(x + (size_t)(tok0 + t) * DIM + k0 + 4 * kq);
    }
    wv[0] = *(const float4*)(wg + (size_t)we * DIM + k0 + 4 * wkq);
    wv[1] = *(const float4*)(wg + (size_t)we * DIM + k0 + 4 * (wkq + 4));

    for (int kc = 0; kc < KSLICE; kc += KC) {
        __syncthreads();
#pragma unroll
        for (int r = 0; r < 4; ++r) {
            int idx = tid + 256 * r;
            int t = idx >> 3, k4 = (idx & 7) * 4;
            xs[k4 + 0][t] = xv[r].x; xs[k4 + 1][t] = xv[r].y;
            xs[k4 + 2][t] = xv[r].z; xs[k4 + 3][t] = xv[r].w;
        }
        {
            int k4 = 4 * wkq;
            wsh[k4 + 0][we] = wv[0].x; wsh[k4 + 1][we] = wv[0].y;
            wsh[k4 + 2][we] = wv[0].z; wsh[k4 + 3][we] = wv[0].w;
            int k4b = k4 + 16;
            wsh[k4b + 0][we] = wv[1].x; wsh[k4b + 1][we] = wv[1].y;
            wsh[k4b + 2][we] = wv[1].z; wsh[k4b + 3][we] = wv[1].w;
        }
        __syncthreads();
        if (kc + KC < KSLICE) {
#pragma unroll
            for (int r = 0; r < 4; ++r) {
                int idx = tid + 256 * r;
                int t = idx >> 3, kq = idx & 7;
                xv[r] = *(const float4*)(x + (size_t)(tok0 + t) * DIM + k0 + kc + KC + 4 * kq);
            }
            wv[0] = *(const float4*)(wg + (size_t)we * DIM + k0 + kc + KC + 4 * wkq);
            wv[1] = *(const float4*)(wg + (size_t)we * DIM + k0 + kc + KC + 4 * (wkq + 4));
        }
#pragma unroll 8
        for (int k = 0; k < KC; ++k) {
            float4 a0 = *(const float4*)&xs[k][8 * tt];
            float4 a1 = *(const float4*)&xs[k][8 * tt + 4];
            float4 b  = *(const float4*)&wsh[k][4 * te];
            const float* ap0 = &a0.x; const float* ap1 = &a1.x; const float* bp = &b.x;
#pragma unroll
            for (int i = 0; i < 4; ++i)
#pragma unroll
                for (int j = 0; j < 4; ++j) {
                    acc[i][j]     += ap0[i] * bp[j];
                    acc[i + 4][j] += ap1[i] * bp[j];
                }
        }
    }

#pragma unroll
    for (int i = 0; i < 8; ++i) {
        size_t off = ((size_t)slice * S_TOK + tok0 + 8 * tt + i) * NEXP + 4 * te;
        float4 v = { acc[i][0], acc[i][1], acc[i][2], acc[i][3] };
        *(float4*)(P + off) = v;
    }
}

// ---------------------------------------------------------------------------
// Kernel 2: reduce 4 partials + softmax + argmax + gsum (blocks 0-255)
//           + zero region B (blocks 256-1023)
// ---------------------------------------------------------------------------
__global__ __launch_bounds__(256) void reduce_zero_b(
    const float* __restrict__ P,
    int* __restrict__ idx_out, float* __restrict__ gate_out,
    float* __restrict__ gsum, float* __restrict__ out)
{
    const int tid = threadIdx.x;

    if (blockIdx.x >= 256) {
        zero_quads(out, QA, QB, 768, blockIdx.x - 256);
        return;
    }

    __shared__ float sme[NEXP];
    const int tok0 = blockIdx.x * 32;
    const int ty = tid >> 5;
    const int tx = tid & 31;
    const int t0 = ty * 4;
    const int e0 = tx * 2;

    if (tid < NEXP) sme[tid] = 0.0f;
    __syncthreads();

    float gm0 = 0.0f, gm1 = 0.0f;
#pragma unroll
    for (int i = 0; i < 4; ++i) {
        int tok = tok0 + t0 + i;
        float l0 = 0.0f, l1 = 0.0f;
#pragma unroll
        for (int s = 0; s < NSLICE; ++s) {
            float2 p = *(const float2*)&P[((size_t)s * S_TOK + tok) * NEXP + e0];
            l0 += p.x; l1 += p.y;
        }
        float v; int ix;
        if (l1 > l0) { v = l1; ix = e0 + 1; } else { v = l0; ix = e0; }
#pragma unroll
        for (int off = 16; off; off >>= 1) {
            float ov = __shfl_xor(v, off, 32);
            int   oi = __shfl_xor(ix, off, 32);
            if (ov > v || (ov == v && oi < ix)) { v = ov; ix = oi; }
        }
        float z0 = __expf(l0 - v), z1 = __expf(l1 - v);
        float zs = z0 + z1;
#pragma unroll
        for (int off = 16; off; off >>= 1) zs += __shfl_xor(zs, off, 32);
        float inv = 1.0f / zs;
        gm0 += z0 * inv; gm1 += z1 * inv;
        if (tx == 0) {
            idx_out[tok]  = ix;
            gate_out[tok] = inv;
        }
    }
    atomicAdd(&sme[e0], gm0);
    atomicAdd(&sme[e0 + 1], gm1);
    __syncthreads();
    if (tid < NEXP) atomicAdd(&gsum[tid], sme[tid]);
}

// ---------------------------------------------------------------------------
// Kernel 3: block 0 = ballot-rank scan -> loc[] + l_aux; blocks 1-256 zero
// region C. 1024 threads.
// ---------------------------------------------------------------------------
__global__ __launch_bounds__(1024) void scan_zero_c(
    const int* __restrict__ idx, const float* __restrict__ gsum,
    int* __restrict__ loc_out, float* __restrict__ out)
{
    const int tid = threadIdx.x;

    if (blockIdx.x > 0) {
        zero_quads(out, QB, NQUAD, 256, (int)blockIdx.x - 1);
        return;
    }

    __shared__ int wavecnt[16][NEXP];
    __shared__ int basecnt[NEXP];
    const int lane = tid & 63;
    const int wv   = tid >> 6;

    if (tid < NEXP) basecnt[tid] = 0;
    __syncthreads();

    for (int it = 0; it < S_TOK / 1024; ++it) {
        int tok = it * 1024 + tid;
        int e = idx[tok];
        unsigned long long m = ~0ull, lm = ~0ull;
#pragma unroll
        for (int b = 0; b < 6; ++b) {
            unsigned long long bal = __ballot((e >> b) & 1);
            m  &= ((e >> b) & 1)    ? bal : ~bal;
            lm &= ((lane >> b) & 1) ? bal : ~bal;
        }
        int rank = __popcll(m & ((1ull << lane) - 1ull));
        wavecnt[wv][lane] = __popcll(lm);
        __syncthreads();
        int off = 0;
        for (int w = 0; w < wv; ++w) off += wavecnt[w][e];
        loc_out[tok] = basecnt[e] + off + rank;   // >= CAP means dropped
        __syncthreads();
        if (tid < NEXP) {
            int tot = 0;
#pragma unroll
            for (int w = 0; w < 16; ++w) tot += wavecnt[w][tid];
            basecnt[tid] += tot;
        }
        __syncthreads();
    }

    if (tid < NEXP) {
        float p = gsum[tid] * (float)basecnt[tid];
#pragma unroll
        for (int off = 32; off; off >>= 1) p += __shfl_xor(p, off, 64);
        if (tid == 0) out[0] = p * 9.5367431640625e-07f;  // 64/8192^2
    }
}

// ---------------------------------------------------------------------------
// Kernel 4: sparse scatter into fully-zeroed output. One token per thread.
// ---------------------------------------------------------------------------
__global__ __launch_bounds__(256) void scatter_kernel(
    const int* __restrict__ idx, const float* __restrict__ gate,
    const int* __restrict__ loc, float* __restrict__ out)
{
    int t = blockIdx.x * 256 + threadIdx.x;
    int l = loc[t];
    if (l < CAP) {
        size_t base = 1 + (size_t)t * (NEXP * CAP) + (size_t)idx[t] * CAP + l;
        out[base] = gate[t];              // combine_weights
        out[base + COMB_ELEMS] = 1.0f;    // dispatch_mask
    }
}

extern "C" void kernel_launch(void* const* d_in, const int* in_sizes, int n_in,
                              void* d_out, int out_size, void* d_ws, size_t ws_size,
                              hipStream_t stream) {
    const float* x  = (const float*)d_in[0];   // [8192, 2048] fp32
    const float* wg = (const float*)d_in[1];   // [64, 2048] fp32
    float* out = (float*)d_out;

    // ws layout
    int*   idx  = (int*)d_ws;                             // 32 KB
    float* gate = (float*)((char*)d_ws + 32768);          // 32 KB
    float* gsum = (float*)((char*)d_ws + 65536);          // 256 B
    int*   loc  = (int*)((char*)d_ws + 66560);            // 32 KB
    float* P    = (float*)((char*)d_ws + 262144);         // 8 MB partials

    gemm_zero_a<<<1024, 256, 0, stream>>>(x, wg, P, gsum, out);
    reduce_zero_b<<<1024, 256, 0, stream>>>(P, idx, gate, gsum, out);
    scan_zero_c<<<257, 1024, 0, stream>>>(idx, gsum, loc, out);
    scatter_kernel<<<S_TOK / 256, 256, 0, stream>>>(idx, gate, loc, out);
}